// Round 6
// baseline (1003.895 us; speedup 1.0000x reference)
//
#include <hip/hip_runtime.h>

#define B_ 128
#define T_ 1024
#define I_ 128
#define H_ 256
#define O_ 64

// DPP quad_perm helpers: add value from lane (in-quad) partner
#define QP_XOR1 0xB1   // quad_perm [1,0,3,2]  (swap pairs)
#define QP_XOR2 0x4E   // quad_perm [2,3,0,1]  (swap halves)

template <int CTRL>
__device__ __forceinline__ float qadd(float x) {
    int yi = __builtin_amdgcn_update_dpp(0, __float_as_int(x), CTRL, 0xF, 0xF, true);
    return x + __int_as_float(yi);
}
__device__ __forceinline__ float fma4(float4 w, float4 h, float a) {
    a = fmaf(w.x, h.x, a); a = fmaf(w.y, h.y, a);
    a = fmaf(w.z, h.z, a); a = fmaf(w.w, h.w, a);
    return a;
}

// ---------------------------------------------------------------------------
// Phase A (R4/R5 structure): xw[row,j] = x[row,:] . W_xh[j,:] + b_h[j]
// ---------------------------------------------------------------------------
__global__ __launch_bounds__(256, 2)
void xw_gemm_kernel(const float* __restrict__ x, const float* __restrict__ W_xh,
                    const float* __restrict__ b_h, float* __restrict__ xw)
{
    const int tid = threadIdx.x;
    const int jb  = tid & 31;
    const int kb  = tid >> 5;                       // 0..7
    __shared__ __align__(16) float xs[2][8 * I_];
    __shared__ __align__(16) float part[64 * 264];

    float4 w[8][4];
#pragma unroll
    for (int a = 0; a < 8; ++a) {
        const float* wr = W_xh + (size_t)(jb * 8 + a) * I_ + kb * 16;
#pragma unroll
        for (int c4 = 0; c4 < 4; ++c4)
            w[a][c4] = reinterpret_cast<const float4*>(wr)[c4];
    }
    const float bh = b_h[tid];

    const int base = blockIdx.x * 256;
    {
        const float4* xp = reinterpret_cast<const float4*>(x + (size_t)base * I_);
        reinterpret_cast<float4*>(xs[0])[tid] = xp[tid];
    }
    __syncthreads();

    int buf = 0;
    for (int tile = 0; tile < 32; ++tile) {
        float4 pre = make_float4(0.f, 0.f, 0.f, 0.f);
        if (tile + 1 < 32) {
            const float4* xp = reinterpret_cast<const float4*>(
                x + (size_t)(base + (tile + 1) * 8) * I_);
            pre = xp[tid];
        }
        float4* p4 = reinterpret_cast<float4*>(part);
#pragma unroll 1
        for (int r = 0; r < 8; ++r) {
            const float4* xr = reinterpret_cast<const float4*>(
                xs[buf] + r * I_ + kb * 16);
            float acc[8];
#pragma unroll
            for (int a = 0; a < 8; ++a) acc[a] = 0.f;
#pragma unroll
            for (int c4 = 0; c4 < 4; ++c4) {
                const float4 xv = xr[c4];
#pragma unroll
                for (int a = 0; a < 8; ++a) acc[a] = fma4(w[a][c4], xv, acc[a]);
            }
            const int rowb = (kb * 8 + r) * 66;
            p4[rowb + ((jb * 2 + 0) ^ kb)] = make_float4(acc[0], acc[1], acc[2], acc[3]);
            p4[rowb + ((jb * 2 + 1) ^ kb)] = make_float4(acc[4], acc[5], acc[6], acc[7]);
        }
        __syncthreads();
        {
            const int q = tid >> 2, m = tid & 3;
            float* orow = xw + (size_t)(base + tile * 8) * H_ + tid;
#pragma unroll
            for (int r = 0; r < 8; ++r) {
                float s = 0.f;
#pragma unroll
                for (int g = 0; g < 8; ++g)
                    s += part[(g * 8 + r) * 264 + (((q ^ g) << 2) | m)];
                orow[(size_t)r * H_] = s + bh;
            }
        }
        if (tile + 1 < 32)
            reinterpret_cast<float4*>(xs[buf ^ 1])[tid] = pre;
        __syncthreads();
        buf ^= 1;
    }
}

// ---------------------------------------------------------------------------
// Phase B: fused recurrence + out-projection, ONE barrier per step.
// 128 WGs x 512 thr, one per batch row.
// Lane (w=tid>>6, q=(tid&63)>>2, p=tid&3):
//   W_hh rows j in [q*16+(p&1)*8,+8) x k in [w*32+(p>>1)*16,+16)  (128 VGPR)
//   W_out rows o in [q*4+(p&1)*2,+2) same k                        (32 VGPR)
// Invariant: the h-slice a lane consumes (k0) lies inside the 32-float slice
// its OWN wave produces in the reduce -> h handoff is wave-local (no barrier,
// just s_waitcnt lgkmcnt(0); DS ops per-wave are in order). Cross-wave
// traffic is only the partials, double-buffered -> single __syncthreads().
// Loop body:
//   A: hr <- own-wave hs slice (4x b128, 2-addr broadcast)
//   B: 160 fma -> quad DPP k-half merge -> p<2 write part[t&1] (2x b128)
//      + opart[t&1] (b64)
//   C: __syncthreads()
//   D: all waves: 4x b32 part reads + pair DPP -> +xw, relu -> hs (own slice);
//      wave 7: reduce opart -> coalesced global store out_{t-1};
//      even lanes: shift xw prefetch pipeline (depth 2)
// ---------------------------------------------------------------------------
__global__ __launch_bounds__(512, 1)
void rnn_scan_kernel(const float* __restrict__ xw, const float* __restrict__ W_hh,
                     const float* __restrict__ W_out, const float* __restrict__ b_out,
                     float* __restrict__ out)
{
    const int tid = threadIdx.x;
    const int w   = tid >> 6;                 // wave 0..7
    const int l   = tid & 63;
    const int q   = l >> 2;                   // 0..15
    const int p   = l & 3;                    // 0..3
    const int r   = blockIdx.x;

    __shared__ __align__(16) float hs[H_];           // wave-private 32-f slices
    __shared__ __align__(16) float part[2][8 * 260]; // double-buffered
    __shared__ __align__(16) float opart[2][8 * 68];

    const int jbase = q * 16 + (p & 1) * 8;
    const int obase = q * 4 + (p & 1) * 2;
    const int k0    = w * 32 + (p >> 1) * 16;
    const int j0    = w * 32 + (l >> 1);      // h-output this lane reduces

    float4 wa[8][4];
#pragma unroll
    for (int a = 0; a < 8; ++a) {
        const float* wr = W_hh + (size_t)(jbase + a) * H_ + k0;
#pragma unroll
        for (int c4 = 0; c4 < 4; ++c4)
            wa[a][c4] = reinterpret_cast<const float4*>(wr)[c4];
    }
    float4 wo[2][4];
#pragma unroll
    for (int d = 0; d < 2; ++d) {
        const float* wr = W_out + (size_t)(obase + d) * H_ + k0;
#pragma unroll
        for (int c4 = 0; c4 < 4; ++c4)
            wo[d][c4] = reinterpret_cast<const float4*>(wr)[c4];
    }

    const float* xwrow = xw + (size_t)r * T_ * H_;
    float* outrow = out + (size_t)r * T_ * O_;
    const float bo = (w == 7) ? b_out[l] : 0.f;

    // ---- peel t=0: h_0 = relu(xw_0), wave-private hs write ----
    float xwreg = 0.f, xwn1 = 0.f, xwn2 = 0.f;
    if ((l & 1) == 0) {
        hs[j0] = fmaxf(xwrow[j0], 0.f);
        xwreg = xwrow[(size_t)1 * H_ + j0];
        xwn1  = xwrow[(size_t)2 * H_ + j0];
    }

#pragma unroll 1
    for (int t = 1; t < T_; ++t) {
        const int buf = t & 1;

        // ensure own-wave hs writes (prev D / peel) have landed
        asm volatile("s_waitcnt lgkmcnt(0)" ::: "memory");

        // --- A: hr <- h_{t-1} slice (wave-local) ---
        float4 hr[4];
        {
            const float4* hp = reinterpret_cast<const float4*>(hs + k0);
#pragma unroll
            for (int c4 = 0; c4 < 4; ++c4) hr[c4] = hp[c4];
        }

        // --- B: fmacs + quad merge + partial writes ---
        float acc[8];
#pragma unroll
        for (int a = 0; a < 8; ++a) acc[a] = 0.f;
        float oa0 = 0.f, oa1 = 0.f;
#pragma unroll
        for (int c4 = 0; c4 < 4; ++c4) {
            const float4 hv = hr[c4];
#pragma unroll
            for (int a = 0; a < 8; ++a) acc[a] = fma4(wa[a][c4], hv, acc[a]);
            oa0 = fma4(wo[0][c4], hv, oa0);
            oa1 = fma4(wo[1][c4], hv, oa1);
        }
#pragma unroll
        for (int a = 0; a < 8; ++a) acc[a] = qadd<QP_XOR2>(acc[a]);
        oa0 = qadd<QP_XOR2>(oa0);
        oa1 = qadd<QP_XOR2>(oa1);

        if (p < 2) {
            float4* p4 = reinterpret_cast<float4*>(part[buf] + w * 260);
            const int c = q * 4 + (p & 1) * 2;
            p4[c + 0] = make_float4(acc[0], acc[1], acc[2], acc[3]);
            p4[c + 1] = make_float4(acc[4], acc[5], acc[6], acc[7]);
            reinterpret_cast<float2*>(opart[buf] + w * 68)[obase >> 1] =
                make_float2(oa0, oa1);
        }
        __syncthreads();                       // single barrier per step

        // --- D: distributed reduce + out store + prefetch ---
        if ((l & 1) == 0) {                    // issue xw[t+2] prefetch early
            const int tt = (t + 2 < T_) ? (t + 2) : (T_ - 1);
            xwn2 = xwrow[(size_t)tt * H_ + j0];
        }
        {
            const int gh = (l & 1) * 4;
            float s = part[buf][(gh + 0) * 260 + j0] + part[buf][(gh + 1) * 260 + j0]
                    + part[buf][(gh + 2) * 260 + j0] + part[buf][(gh + 3) * 260 + j0];
            s = qadd<QP_XOR1>(s);              // pair (l, l^1) combine
            if ((l & 1) == 0) {
                const float v = s + xwreg;
                hs[j0] = (v > 0.f) ? v : 0.f;
                xwreg = xwn1; xwn1 = xwn2;
            }
        }
        if (w == 7) {                          // out_{t-1}
            float so = 0.f;
#pragma unroll
            for (int g = 0; g < 8; ++g) so += opart[buf][g * 68 + l];
            outrow[(size_t)(t - 1) * O_ + l] = so + bo;
        }
    }

    // ---- epilogue: out_{T-1} from h_{T-1} ----
    {
        asm volatile("s_waitcnt lgkmcnt(0)" ::: "memory");
        float4 hr[4];
        const float4* hp = reinterpret_cast<const float4*>(hs + k0);
#pragma unroll
        for (int c4 = 0; c4 < 4; ++c4) hr[c4] = hp[c4];
        float oa0 = 0.f, oa1 = 0.f;
#pragma unroll
        for (int c4 = 0; c4 < 4; ++c4) {
            oa0 = fma4(wo[0][c4], hr[c4], oa0);
            oa1 = fma4(wo[1][c4], hr[c4], oa1);
        }
        oa0 = qadd<QP_XOR2>(oa0);
        oa1 = qadd<QP_XOR2>(oa1);
        if (p < 2)
            reinterpret_cast<float2*>(opart[0] + w * 68)[obase >> 1] =
                make_float2(oa0, oa1);
        __syncthreads();
        if (w == 7) {
            float so = 0.f;
#pragma unroll
            for (int g = 0; g < 8; ++g) so += opart[0][g * 68 + l];
            outrow[(size_t)(T_ - 1) * O_ + l] = so + bo;
        }
    }
}

// ---------------------------------------------------------------------------
extern "C" void kernel_launch(void* const* d_in, const int* in_sizes, int n_in,
                              void* d_out, int out_size, void* d_ws, size_t ws_size,
                              hipStream_t stream)
{
    (void)in_sizes; (void)n_in; (void)out_size; (void)ws_size;
    const float* x     = (const float*)d_in[0];   // [B,T,I]
    const float* W_xh  = (const float*)d_in[1];   // [H,I]
    const float* W_hh  = (const float*)d_in[2];   // [H,H]
    const float* b_h   = (const float*)d_in[3];   // [H]
    const float* W_out = (const float*)d_in[4];   // [O,H]
    const float* b_out = (const float*)d_in[5];   // [O]
    float* out = (float*)d_out;                   // [B,T,O]
    float* xw  = (float*)d_ws;                    // [B*T*H] fp32 = 128 MiB scratch

    xw_gemm_kernel<<<512, 256, 0, stream>>>(x, W_xh, b_h, xw);
    rnn_scan_kernel<<<128, 512, 0, stream>>>(xw, W_hh, W_out, b_out, out);
}

// Round 7
// 931.281 us; speedup vs baseline: 1.0780x; 1.0780x over previous
//
#include <hip/hip_runtime.h>

#define B_ 128
#define T_ 1024
#define I_ 128
#define H_ 256
#define O_ 64

__device__ __forceinline__ float fma4(float4 w, float4 h, float a) {
    a = fmaf(w.x, h.x, a); a = fmaf(w.y, h.y, a);
    a = fmaf(w.z, h.z, a); a = fmaf(w.w, h.w, a);
    return a;
}

// ---------------------------------------------------------------------------
// Phase A (R4 structure, unchanged): xw[row,j] = x[row,:] . W_xh[j,:] + b_h[j]
// ---------------------------------------------------------------------------
__global__ __launch_bounds__(256, 2)
void xw_gemm_kernel(const float* __restrict__ x, const float* __restrict__ W_xh,
                    const float* __restrict__ b_h, float* __restrict__ xw)
{
    const int tid = threadIdx.x;
    const int jb  = tid & 31;
    const int kb  = tid >> 5;                       // 0..7
    __shared__ __align__(16) float xs[2][8 * I_];
    __shared__ __align__(16) float part[64 * 264];

    float4 w[8][4];
#pragma unroll
    for (int a = 0; a < 8; ++a) {
        const float* wr = W_xh + (size_t)(jb * 8 + a) * I_ + kb * 16;
#pragma unroll
        for (int c4 = 0; c4 < 4; ++c4)
            w[a][c4] = reinterpret_cast<const float4*>(wr)[c4];
    }
    const float bh = b_h[tid];

    const int base = blockIdx.x * 256;
    {
        const float4* xp = reinterpret_cast<const float4*>(x + (size_t)base * I_);
        reinterpret_cast<float4*>(xs[0])[tid] = xp[tid];
    }
    __syncthreads();

    int buf = 0;
    for (int tile = 0; tile < 32; ++tile) {
        float4 pre = make_float4(0.f, 0.f, 0.f, 0.f);
        if (tile + 1 < 32) {
            const float4* xp = reinterpret_cast<const float4*>(
                x + (size_t)(base + (tile + 1) * 8) * I_);
            pre = xp[tid];
        }
        float4* p4 = reinterpret_cast<float4*>(part);
#pragma unroll 1
        for (int r = 0; r < 8; ++r) {
            const float4* xr = reinterpret_cast<const float4*>(
                xs[buf] + r * I_ + kb * 16);
            float acc[8];
#pragma unroll
            for (int a = 0; a < 8; ++a) acc[a] = 0.f;
#pragma unroll
            for (int c4 = 0; c4 < 4; ++c4) {
                const float4 xv = xr[c4];
#pragma unroll
                for (int a = 0; a < 8; ++a) acc[a] = fma4(w[a][c4], xv, acc[a]);
            }
            const int rowb = (kb * 8 + r) * 66;
            p4[rowb + ((jb * 2 + 0) ^ kb)] = make_float4(acc[0], acc[1], acc[2], acc[3]);
            p4[rowb + ((jb * 2 + 1) ^ kb)] = make_float4(acc[4], acc[5], acc[6], acc[7]);
        }
        __syncthreads();
        {
            const int q = tid >> 2, m = tid & 3;
            float* orow = xw + (size_t)(base + tile * 8) * H_ + tid;
#pragma unroll
            for (int r = 0; r < 8; ++r) {
                float s = 0.f;
#pragma unroll
                for (int g = 0; g < 8; ++g)
                    s += part[(g * 8 + r) * 264 + (((q ^ g) << 2) | m)];
                orow[(size_t)r * H_] = s + bh;
            }
        }
        if (tile + 1 < 32)
            reinterpret_cast<float4*>(xs[buf ^ 1])[tid] = pre;
        __syncthreads();
        buf ^= 1;
    }
}

// ---------------------------------------------------------------------------
// Phase B: R4 structure (2 barriers, LDS 16-deep reduce) + LDS-STAGED xw.
// xw is consumed via LDS chunks of 16 timesteps (2 x 16 KB double buffer).
// Chunk c+2's global loads are issued a full 16 steps before their LDS write,
// so the compiler's vmcnt wait is free -> no per-step global-latency stall
// (the flaw in R1-R6's register-shift prefetch).
//   phase 1 (all 8 waves): recurrence fmacs -> part (swizzled, stride 264);
//                          out-proj fmacs on h_{t-1} -> opart
//   barrier (1)
//   phase 2: waves 0-3 reduce part + xws(ds_read) + relu -> hs;
//            wave 4 reduces opart -> global store out_{t-1}
//   barrier (2)
//   all: hr <- hs; every 16th step: stg->xws[other], issue next chunk loads
// ---------------------------------------------------------------------------
__global__ __launch_bounds__(512, 1)
void rnn_scan_kernel(const float* __restrict__ xw, const float* __restrict__ W_hh,
                     const float* __restrict__ W_out, const float* __restrict__ b_out,
                     float* __restrict__ out)
{
    const int tid = threadIdx.x;
    const int jb  = tid & 31;
    const int kb  = tid >> 5;                 // 0..15
    const int r   = blockIdx.x;               // batch row

    __shared__ __align__(16) float hs[H_];
    __shared__ __align__(16) float part[16 * 264];   // 16.9 KB
    __shared__ __align__(16) float opart[16 * 64];   // 4 KB
    __shared__ __align__(16) float xws[2][16 * H_];  // 32 KB staged xw

    float4 wa[8][4];
#pragma unroll
    for (int a = 0; a < 8; ++a) {
        const float* wr = W_hh + (size_t)(jb * 8 + a) * H_ + kb * 16;
#pragma unroll
        for (int c4 = 0; c4 < 4; ++c4)
            wa[a][c4] = reinterpret_cast<const float4*>(wr)[c4];
    }
    float4 wo[2][4];
#pragma unroll
    for (int d = 0; d < 2; ++d) {
        const float* wr = W_out + (size_t)(jb * 2 + d) * H_ + kb * 16;
#pragma unroll
        for (int c4 = 0; c4 < 4; ++c4)
            wo[d][c4] = reinterpret_cast<const float4*>(wr)[c4];
    }

    const float* xwrow = xw + (size_t)r * T_ * H_;
    float* outrow = out + (size_t)r * T_ * O_;
    const float bo = (tid >= 256 && tid < 320) ? b_out[tid - 256] : 0.f;

    // ---- stage chunk 0 into xws[0]; issue chunk 1 loads into stg ----
    float4 stg0, stg1;
    {
        const float4* g = reinterpret_cast<const float4*>(xwrow);
        stg0 = g[tid]; stg1 = g[tid + 512];
        float4* l = reinterpret_cast<float4*>(xws[0]);
        l[tid] = stg0; l[tid + 512] = stg1;   // compiler inserts vmcnt wait
        const float4* g1 = reinterpret_cast<const float4*>(xwrow + 16 * H_);
        stg0 = g1[tid]; stg1 = g1[tid + 512];
    }
    __syncthreads();

    // ---- peel t=0: h_0 = relu(xw_0) ----
    if (tid < 256) hs[tid] = fmaxf(xws[0][tid], 0.f);
    __syncthreads();

    float4 hr[4];
    {
        const float4* hs4 = reinterpret_cast<const float4*>(hs);
#pragma unroll
        for (int c4 = 0; c4 < 4; ++c4) hr[c4] = hs4[kb * 4 + c4];
    }

#pragma unroll 1
    for (int t = 1; t < T_; ++t) {
        // --- phase 1: recurrence + out-proj fmacs ---
        float acc[8];
#pragma unroll
        for (int a = 0; a < 8; ++a) acc[a] = 0.f;
        float oa0 = 0.f, oa1 = 0.f;
#pragma unroll
        for (int c4 = 0; c4 < 4; ++c4) {
            const float4 hv = hr[c4];
#pragma unroll
            for (int a = 0; a < 8; ++a) acc[a] = fma4(wa[a][c4], hv, acc[a]);
            oa0 = fma4(wo[0][c4], hv, oa0);
            oa1 = fma4(wo[1][c4], hv, oa1);
        }
        {   // swizzled partial writes, row-stride 264 (66 float4)
            float4* p4 = reinterpret_cast<float4*>(part);
            p4[kb * 66 + ((jb * 2 + 0) ^ kb)] = make_float4(acc[0], acc[1], acc[2], acc[3]);
            p4[kb * 66 + ((jb * 2 + 1) ^ kb)] = make_float4(acc[4], acc[5], acc[6], acc[7]);
            reinterpret_cast<float2*>(opart)[kb * 32 + jb] = make_float2(oa0, oa1);
        }
        __syncthreads();                      // (1)

        // --- phase 2: concurrent reductions ---
        if (tid < 256) {                      // waves 0-3: h_t
            const int q = tid >> 2, m = tid & 3;
            float s = 0.f;
#pragma unroll
            for (int g = 0; g < 16; ++g)
                s += part[g * 264 + (((q ^ g) << 2) | m)];
            s += xws[(t >> 4) & 1][(t & 15) * H_ + tid];   // LDS, latency-free
            hs[tid] = (s > 0.f) ? s : 0.f;
        } else if (tid < 320) {               // wave 4: out_{t-1}
            const int to = tid - 256;
            float s = 0.f;
#pragma unroll
            for (int g = 0; g < 16; ++g) s += opart[g * 64 + to];
            outrow[(size_t)(t - 1) * O_ + to] = s + bo;
        }
        __syncthreads();                      // (2)

        {   // hr <- h_t
            const float4* hs4 = reinterpret_cast<const float4*>(hs);
#pragma unroll
            for (int c4 = 0; c4 < 4; ++c4) hr[c4] = hs4[kb * 4 + c4];
        }

        // --- chunk maintenance every 16th step ---
        if ((t & 15) == 15 && t + 1 < T_) {
            const int c = t >> 4;                       // chunk just finished
            float4* l = reinterpret_cast<float4*>(xws[(c + 1) & 1]);
            l[tid] = stg0; l[tid + 512] = stg1;         // loads 16 steps old
            if (c + 2 < T_ / 16) {
                const float4* g = reinterpret_cast<const float4*>(
                    xwrow + (size_t)(c + 2) * 16 * H_);
                stg0 = g[tid]; stg1 = g[tid + 512];     // for 16 steps hence
            }
        }
    }

    // ---- epilogue: out_{T-1} from hr = h_{T-1} ----
    {
        float oa0 = 0.f, oa1 = 0.f;
#pragma unroll
        for (int c4 = 0; c4 < 4; ++c4) {
            oa0 = fma4(wo[0][c4], hr[c4], oa0);
            oa1 = fma4(wo[1][c4], hr[c4], oa1);
        }
        reinterpret_cast<float2*>(opart)[kb * 32 + jb] = make_float2(oa0, oa1);
        __syncthreads();
        if (tid >= 256 && tid < 320) {
            const int to = tid - 256;
            float s = 0.f;
#pragma unroll
            for (int g = 0; g < 16; ++g) s += opart[g * 64 + to];
            outrow[(size_t)(T_ - 1) * O_ + to] = s + bo;
        }
    }
}

// ---------------------------------------------------------------------------
extern "C" void kernel_launch(void* const* d_in, const int* in_sizes, int n_in,
                              void* d_out, int out_size, void* d_ws, size_t ws_size,
                              hipStream_t stream)
{
    (void)in_sizes; (void)n_in; (void)out_size; (void)ws_size;
    const float* x     = (const float*)d_in[0];   // [B,T,I]
    const float* W_xh  = (const float*)d_in[1];   // [H,I]
    const float* W_hh  = (const float*)d_in[2];   // [H,H]
    const float* b_h   = (const float*)d_in[3];   // [H]
    const float* W_out = (const float*)d_in[4];   // [O,H]
    const float* b_out = (const float*)d_in[5];   // [O]
    float* out = (float*)d_out;                   // [B,T,O]
    float* xw  = (float*)d_ws;                    // [B*T*H] fp32 = 128 MiB scratch

    xw_gemm_kernel<<<512, 256, 0, stream>>>(x, W_xh, b_h, xw);
    rnn_scan_kernel<<<128, 512, 0, stream>>>(xw, W_hh, W_out, b_out, out);
}